// Round 16
// baseline (83.449 us; speedup 1.0000x reference)
//
#include <hip/hip_runtime.h>

typedef float __attribute__((ext_vector_type(4))) f32x4;
typedef unsigned int u32;
typedef u32 __attribute__((ext_vector_type(4))) u32x4;

// OUT[n, c=j*8+k, h, w] = sum_{a,m,b} W[j,a,m,b,k] * T[n,(j+a-1)*4+m, (h-1)%28, (w+b-2)%28]
//   T[n,cc,h,w] = x[n,cc,h,w] + x[n,cc+128,h,w]
//   (j+a-1) outside [0,32) -> zero; (w+b-1) outside [0,28) -> zero (w unfold pad)
//
// R16 = R14 (50.3 us, all counters clean) + 2 h-pairs per block with register prefetch:
//   P1's staging loads are issued BEFORE P0's tail, so their HBM/L2 latency hides under
//   the tail's LDS round-trip + stores. Straight-line (no runtime loop -> no spill,
//   R3/R4 lesson), plain loads (compiler waits, R5 lesson), layout/run-lengths unchanged
//   from R14 (R15 lesson). Separate tail LDS region so P1 input and P0 tail coexist.
// Block = (n, h-quad, channel-half): 256 thr; LDS 24.6 KB -> 6 blocks/CU; 1792 blocks.
// Verified pieces byte-for-byte from R14: bf16-pair m-packed staging (224B-run loads,
//   zero-filled halo), swizzle slot=q^(gl&7) (conflict-free), dot2 compute, 2-round
//   64-ch tail with 224B-run stores (WRITE==100.35MB exact).

__device__ __forceinline__ u32 pack2bf(float lo, float hi) {
    u32 a = __float_as_uint(lo), b = __float_as_uint(hi);
    a = (a + 0x7FFFu + ((a >> 16) & 1u)) >> 16;   // RNE round to bf16
    b = (b + 0x7FFFu + ((b >> 16) & 1u)) >> 16;
    return a | (b << 16);
}

__device__ __forceinline__ float dot2bf(u32 t2, u32 w2, float acc) {
    asm("v_dot2_f32_bf16 %0, %1, %2, %0" : "+v"(acc) : "v"(t2), "v"(w2));
    return acc;
}

__device__ __forceinline__ void compute_row(const u32* Bs, const u32 (*w2)[2][3],
                                            int jl, float* acc) {
    #pragma unroll
    for (int w = 0; w < 28; ++w) acc[w] = 0.f;
    #pragma unroll
    for (int a = 0; a < 3; ++a) {
        const int gl = jl + a;              // local group 0..17, always in window
        const int s  = gl & 7;
        #pragma unroll
        for (int m2 = 0; m2 < 2; ++m2) {
            const int rowd = (gl * 2 + m2) * 32;
            const u32 t2 = w2[a][m2][2], t1 = w2[a][m2][1], t0 = w2[a][m2][0];
            #pragma unroll
            for (int qb = 0; qb < 7; ++qb) {
                const u32x4 v = *(const u32x4*)&Bs[rowd + ((qb ^ s) << 2)];
                #pragma unroll
                for (int e = 0; e < 4; ++e) {
                    const int wp_ = qb * 4 + e;                              // source col w'
                    if (wp_ != 27) acc[wp_] = dot2bf(v[e], t2, acc[wp_]);    // b=2 tap
                    acc[(wp_ + 1) % 28] = dot2bf(v[e], t1, acc[(wp_ + 1) % 28]); // b=1
                    if (wp_ != 26) acc[(wp_ + 2) % 28] = dot2bf(v[e], t0, acc[(wp_ + 2) % 28]); // b=0
                }
            }
        }
    }
}

__device__ __forceinline__ void tail_store(const float* acc, float* LT, float* outb,
                                           int tid, int tloc, int s_,
                                           const int* rb_c, const int* rb_r) {
    #pragma unroll
    for (int c = 0; c < 2; ++c) {
        __syncthreads();                    // compute / prev-round reads done
        if ((tloc >> 6) == c) {             // 128 owner threads (64 ch x 2 rows) dump
            float* dst = LT + (tloc & 63) * 60 + s_ * 28;
            #pragma unroll
            for (int qq = 0; qq < 7; ++qq) {
                f32x4 o;
                o.x = acc[qq * 4 + 0];
                o.y = acc[qq * 4 + 1];
                o.z = acc[qq * 4 + 2];
                o.w = acc[qq * 4 + 3];
                *(f32x4*)(dst + qq * 4) = o;
            }
        }
        __syncthreads();
        float* outc = outb + (size_t)(c * 64) * 784;
        #pragma unroll
        for (int it = 0; it < 4; ++it) {
            if (tid + it * 256 < 896) {
                const f32x4 v = *(const f32x4*)(LT + rb_c[it] * 60 + rb_r[it] * 4);
                *(f32x4*)(outc + (size_t)rb_c[it] * 784 + rb_r[it] * 4) = v;
            }
        }
    }
}

__global__ __launch_bounds__(256, 6) void fused_shift_conv(
    const float* __restrict__ x, const float* __restrict__ Wt, float* __restrict__ out)
{
    __shared__ __align__(16) u32   LIN[2304];   // input 2 rows x 36 pairs x 32 dw, 9.2 KB
    __shared__ __align__(16) float LT[3840];    // tail [64 ch][60], 15 KB

    const int tid  = threadIdx.x;
    const int blk  = blockIdx.x;
    const int half = blk & 1;               // channel half: j in [J0, J0+16)
    const int rest = blk >> 1;
    const int n    = rest / 7;
    const int q4   = rest - n * 7;
    const int h0   = q4 * 4;                // rows h0..h0+3; P0=(h0,h0+1) P1=(h0+2,h0+3)
    const int J0   = half * 16;

    const float* xn = x + (size_t)n * 200704;

    // ---- staging descriptors (shared by P0 stage / P1 prefetch) ----
    int ldso[2], chq[2], rowv[2];
    bool val[2], okg[2];
    #pragma unroll
    for (int it = 0; it < 2; ++it) {
        const int f = tid + it * 256;
        val[it] = f < 504;
        const int pl  = f / 14;             // local pair 0..35 (when valid)
        const int rem = f - pl * 14;
        const int row = rem / 7;            // input row 0..1 of the pair
        const int q   = rem - row * 7;      // quad 0..6
        const int gl  = pl >> 1;            // local group 0..17
        const int mp  = pl & 1;
        const int g   = J0 - 1 + gl;        // global group -1..32
        rowv[it] = row;
        okg[it]  = val[it] && g >= 0 && g <= 31;
        chq[it]  = okg[it] ? ((g * 4 + mp * 2) * 784 + q * 4) : 0;
        ldso[it] = row * 1152 + pl * 32 + ((q ^ (gl & 7)) << 2);
    }

    // ---- stage P0 (input rows h0-1 [wrap], h0) ----
    #pragma unroll
    for (int it = 0; it < 2; ++it) {
        if (val[it]) {
            int hs = h0 - 1 + rowv[it]; if (hs < 0) hs = 27;
            u32x4 wv = {0u, 0u, 0u, 0u};    // halo groups stay zero (0*W safe)
            if (okg[it]) {
                const float* b0 = xn + chq[it] + hs * 28;
                const f32x4 l0 = *(const f32x4*)b0;
                const f32x4 l1 = *(const f32x4*)(b0 + 784);
                const f32x4 u0 = *(const f32x4*)(b0 + 100352);
                const f32x4 u1 = *(const f32x4*)(b0 + 100352 + 784);
                const f32x4 s0 = l0 + u0, s1 = l1 + u1;
                wv[0] = pack2bf(s0[0], s1[0]);
                wv[1] = pack2bf(s0[1], s1[1]);
                wv[2] = pack2bf(s0[2], s1[2]);
                wv[3] = pack2bf(s0[3], s1[3]);
            }
            *(u32x4*)&LIN[ldso[it]] = wv;
        }
    }

    // ---- per-thread weights: tloc = tid&127 owns c = (J0+jl)*8+k; s_ = row in pair ----
    const int tloc = tid & 127;
    const int s_   = tid >> 7;
    const int jl   = tloc >> 3;             // 0..15
    const int j    = J0 + jl;
    const int k    = tloc & 7;
    u32 w2[3][2][3];                        // [a][m-pair][tap], bf16-pair packed
    {
        const float* wp = Wt + j * 288 + k; // W[j,a,m,b,k] strides 288/96/24/8/1
        #pragma unroll
        for (int a = 0; a < 3; ++a)
            #pragma unroll
            for (int m2 = 0; m2 < 2; ++m2)
                #pragma unroll
                for (int bb = 0; bb < 3; ++bb)
                    w2[a][m2][bb] = pack2bf(wp[a*96 + (2*m2  )*24 + bb*8],
                                            wp[a*96 + (2*m2+1)*24 + bb*8]);
    }
    if (j == 0) {
        #pragma unroll
        for (int m2 = 0; m2 < 2; ++m2)
            #pragma unroll
            for (int bb = 0; bb < 3; ++bb) w2[0][m2][bb] = 0u;
    }
    if (j == 31) {
        #pragma unroll
        for (int m2 = 0; m2 < 2; ++m2)
            #pragma unroll
            for (int bb = 0; bb < 3; ++bb) w2[2][m2][bb] = 0u;
    }

    // ---- hoisted tail readback indices (round-invariant) ----
    int rb_c[4], rb_r[4];
    #pragma unroll
    for (int it = 0; it < 4; ++it) {
        const int fo = tid + it * 256;
        rb_c[it] = fo / 14;                 // local channel 0..63
        rb_r[it] = fo - rb_c[it] * 14;      // f4 within the 224 B (2-row) run
    }

    __syncthreads();

    // ---- compute P0 ----
    float acc0[28];
    compute_row(LIN + s_ * 1152, w2, jl, acc0);

    // ---- prefetch P1 (input rows h0+1, h0+2 — never wrap) into registers ----
    f32x4 pfa[2], pfb[2];
    #pragma unroll
    for (int it = 0; it < 2; ++it) {
        pfa[it] = (f32x4){0.f, 0.f, 0.f, 0.f};
        pfb[it] = (f32x4){0.f, 0.f, 0.f, 0.f};
        if (okg[it]) {
            const int hs = h0 + 1 + rowv[it];
            const float* b0 = xn + chq[it] + hs * 28;
            pfa[it] = *(const f32x4*)b0         + *(const f32x4*)(b0 + 100352);
            pfb[it] = *(const f32x4*)(b0 + 784) + *(const f32x4*)(b0 + 100352 + 784);
        }
    }

    // ---- tail P0 (prefetch latency hides under this) ----
    float* outb0 = out + (size_t)n * 200704 + (size_t)(J0 * 8) * 784 + h0 * 28;
    tail_store(acc0, LT, outb0, tid, tloc, s_, rb_c, rb_r);

    // ---- land prefetch: pack + write P1 input (LIN reads long done; LT disjoint) ----
    #pragma unroll
    for (int it = 0; it < 2; ++it) {
        if (val[it]) {
            u32x4 wv;
            wv[0] = pack2bf(pfa[it][0], pfb[it][0]);
            wv[1] = pack2bf(pfa[it][1], pfb[it][1]);
            wv[2] = pack2bf(pfa[it][2], pfb[it][2]);
            wv[3] = pack2bf(pfa[it][3], pfb[it][3]);
            *(u32x4*)&LIN[ldso[it]] = wv;
        }
    }
    __syncthreads();

    // ---- compute P1 + tail P1 ----
    float acc1[28];
    compute_row(LIN + s_ * 1152, w2, jl, acc1);
    tail_store(acc1, LT, outb0 + 2 * 28, tid, tloc, s_, rb_c, rb_r);
}

extern "C" void kernel_launch(void* const* d_in, const int* in_sizes, int n_in,
                              void* d_out, int out_size, void* d_ws, size_t ws_size,
                              hipStream_t stream) {
    const float* x  = (const float*)d_in[0];   // (128,256,28,28) f32
    const float* Wt = (const float*)d_in[1];   // (32,3,4,3,8)   f32
    float* out      = (float*)d_out;           // (128,256,28,28) f32

    const int nbatch = in_sizes[0] / 200704;   // 128
    // grid: (n, h-quad, channel-half) -> 128*7*2 = 1792 blocks
    fused_shift_conv<<<nbatch * 14, 256, 0, stream>>>(x, Wt, out);
}